// Round 21
// baseline (1863.440 us; speedup 1.0000x reference)
//
#include <hip/hip_runtime.h>

#define T_STEPS 512
#define BATCH   128
#define DIN     256
#define DLAT    512

typedef __bf16 bf16x8 __attribute__((ext_vector_type(8)));
typedef float  f32x4  __attribute__((ext_vector_type(4)));
typedef int    i32x4  __attribute__((ext_vector_type(4)));
typedef unsigned long long u64;

__device__ __forceinline__ unsigned int f2bf2(float a, float b) {
  unsigned int ua = __float_as_uint(a);
  unsigned int ub = __float_as_uint(b);
  ua = (ua + 0x7FFFu + ((ua >> 16) & 1u)) >> 16;
  ub = (ub + 0x7FFFu + ((ub >> 16) & 1u)) >> 16;
  return ua | (ub << 16);
}

__device__ __forceinline__ uint4 pack8(float4 f0, float4 f1) {
  uint4 r;
  r.x = f2bf2(f0.x, f0.y);
  r.y = f2bf2(f0.z, f0.w);
  r.z = f2bf2(f1.x, f1.y);
  r.w = f2bf2(f1.z, f1.w);
  return r;
}

// ---------------- Kernel P: prepack Wh fp32 -> bf16 row-major in workspace ----------------
extern "C" __global__ __launch_bounds__(256) void pk_wh(
    const float* __restrict__ Wh, unsigned int* __restrict__ out) {
  int idx = blockIdx.x * 256 + threadIdx.x;   // 0..32767, 8 f32 each
  const float* src = Wh + (long)idx * 8;
  float4 f0 = *(const float4*)src;
  float4 f1 = *(const float4*)(src + 4);
  uint4 v = pack8(f0, f1);
  *(uint4*)(out + (long)idx * 4) = v;
}

// ---------------- Kernel A: Xi = X @ Wi^T + (bi + bh), written into d_out ----------------
extern "C" __global__ __launch_bounds__(256) void xi_gemm(
    const float* __restrict__ X, const float* __restrict__ Wi,
    const float* __restrict__ bi, const float* __restrict__ bh,
    float* __restrict__ XiOut) {
  extern __shared__ char smem[];
  char*  sX    = smem;                      // 65536 B: [128 rows][512 B] swizzled
  char*  sW    = smem + 65536;              // 65536 B
  float* sBias = (float*)(smem + 131072);   // 128 floats

  const int tid = threadIdx.x;
  const long m0 = (long)blockIdx.x * 128;   // over T*B = 65536
  const int  n0 = blockIdx.y * 128;         // over DLAT

  #pragma unroll
  for (int c = 0; c < 16; ++c) {
    int id = c * 256 + tid;                 // 0..4095
    int r  = id >> 5;                       // 0..127
    int kc = (id & 31) << 3;                // 0..248
    const float* sx = X + (m0 + r) * DIN + kc;
    float4 a0 = *(const float4*)sx;
    float4 a1 = *(const float4*)(sx + 4);
    int ax = ((r << 9) + (kc << 1)) ^ ((r & 7) << 4);
    *(uint4*)(sX + ax) = pack8(a0, a1);
    const float* sw = Wi + (n0 + r) * DIN + kc;
    float4 b0 = *(const float4*)sw;
    float4 b1 = *(const float4*)(sw + 4);
    *(uint4*)(sW + ax) = pack8(b0, b1);
  }
  if (tid < 128) sBias[tid] = bi[n0 + tid] + bh[n0 + tid];
  __syncthreads();

  const int w = tid >> 6, lane = tid & 63;
  const int wm = (w >> 1) * 64, wn = (w & 1) * 64;
  const int lm = lane & 15, lq = lane >> 4;

  f32x4 acc[4][4];
  #pragma unroll
  for (int nt = 0; nt < 4; ++nt) {
    float bv = sBias[wn + nt * 16 + lm];
    #pragma unroll
    for (int mt = 0; mt < 4; ++mt) acc[mt][nt] = f32x4{bv, bv, bv, bv};
  }

  #pragma unroll
  for (int k0 = 0; k0 < 8; ++k0) {
    int kb = (k0 << 6) + (lq << 4);
    bf16x8 af[4], bfr[4];
    #pragma unroll
    for (int mt = 0; mt < 4; ++mt) {
      int row = wm + mt * 16 + lm;
      int ax = ((row << 9) + kb) ^ ((row & 7) << 4);
      af[mt] = __builtin_bit_cast(bf16x8, *(uint4*)(sX + ax));
    }
    #pragma unroll
    for (int nt = 0; nt < 4; ++nt) {
      int row = wn + nt * 16 + lm;
      int ax = ((row << 9) + kb) ^ ((row & 7) << 4);
      bfr[nt] = __builtin_bit_cast(bf16x8, *(uint4*)(sW + ax));
    }
    #pragma unroll
    for (int mt = 0; mt < 4; ++mt)
      #pragma unroll
      for (int nt = 0; nt < 4; ++nt)
        acc[mt][nt] = __builtin_amdgcn_mfma_f32_16x16x32_bf16(af[mt], bfr[nt], acc[mt][nt], 0, 0, 0);
  }

  #pragma unroll
  for (int mt = 0; mt < 4; ++mt) {
    #pragma unroll
    for (int e = 0; e < 4; ++e) {
      long m = m0 + wm + mt * 16 + (lq << 2) + e;
      float* dst = XiOut + m * DLAT + n0 + wn + lm;
      #pragma unroll
      for (int nt = 0; nt < 4; ++nt)
        dst[nt * 16] = acc[mt][nt][e];
    }
  }
}

// ---------------- Kernel B: n-split x4 recurrence, L3-coherent exchange ----------------
// 32 blocks = 8 batch-groups x 4 n-quarters; 512 threads; wave w owns ONE n-tile
// (nt = q*128 + w*16), Wh slice = wreg[16] = 64 regs (AGPR-resident via AV operand
// class). LDS = 2 x 16 KB sH double-buffer.
// r20 lesson: tagged u32 exchange doubled traffic (WRITE 197->393 MB) and lost 46% --
// keep r19's lean 8-B bf16 publish + fused speculative poll. This round removes
// barrier #1 via (a) sH double-buffer (step t reads cur, ALL writes go to nxt -- no
// LDS read/write conflict) and (b) PER-WAVE monotonic flags: each wave publishes,
// drains ITS OWN vmcnt(0), lane0 stores flags[g][q][w] = t+1 (single-writer u32,
// 1 KB total, memset per launch; monotonic so '>= t+1' is replay-safe). Readers'
// fused poll checks 24 flag words (lanes 0-23) + same-iteration 3 data u64s; r19's
// skew argument is per-wave identical (writer data at L3 >= 1 transit before its
// flag visible; same-iteration reader samples skew by only tens of cycles).
// One barrier/step (after commit, before next MFMA reads nxt).
// Depth-2 parity audit: X's t+2 slot overwrite <- X's t+1 barrier <- X's t+1 poll saw
// all Y-wave flags >= t+2 <- stored after each Y-wave's t+1 publish-drain <- after Y's
// step-t barrier <- after Y's step-t commit reads of the slot. Safe under any skew.
extern "C" __global__ __launch_bounds__(512, 2) void rnn_scan(
    const float* __restrict__ h0, const unsigned short* __restrict__ WhP,
    float* __restrict__ HO, u64* __restrict__ hx,
    unsigned int* __restrict__ flags) {
  __shared__ uint4 sHbuf[2048];   // 32 KB: two 16 KB h buffers, XOR-swizzled rows
  char* sB = (char*)sHbuf;

  const int tid = threadIdx.x;
  const int w = tid >> 6, lane = tid & 63;
  const int lm = lane & 15, lq = lane >> 4;
  const int g  = blockIdx.x & 7;      // batch group: rows [g*16, g*16+16)
  const int q  = blockIdx.x >> 3;     // n-quarter:  cols [q*128, q*128+128)
  const int r0 = g << 4;
  const int nt = (q << 7) + (w << 4); // wave's n-tile

  // Wh slice: lane holds Wh[nt+lm][kq*32 + lq*8 .. +7], kq = 0..15 (64 regs)
  i32x4 wreg[16];
  {
    const unsigned short* base = WhP + (nt + lm) * DLAT + (lq << 3);
    #pragma unroll
    for (int kq = 0; kq < 16; ++kq)
      wreg[kq] = *(const i32x4*)(base + kq * 32);
    #pragma unroll
    for (int kq = 0; kq < 16; ++kq)
      asm("" : "+v"(wreg[kq]));   // anti-remat pin (asm def)
  }

  // initial h from h0 into buffer 0: 16 rows x 64 chunks(16B) = 1024 -> 2 iters
  #pragma unroll
  for (int c = 0; c < 2; ++c) {
    int id = c * 512 + tid;
    int m = id >> 6, kc = (id & 63) << 3;
    const float* src = h0 + (r0 + m) * DLAT + kc;
    float4 f0 = *(const float4*)src;
    float4 f1 = *(const float4*)(src + 4);
    int ax = ((m << 10) + (kc << 1)) ^ ((m & 7) << 4);
    *(uint4*)(sB + ax) = pack8(f0, f1);
  }
  __syncthreads();

  const int mask  = (lm & 7) << 4;
  const int hbase = (lm << 10) + (lq << 4);
  const int ncol  = nt + (lq << 2);              // thread's 4 consecutive n (row m = lm)
  u64* hgrp = hx + ((long)g << 11);              // group slab: 2048 u64 = 16 KB
  const int pubi = (lm << 7) + (ncol >> 2);      // publish slot for own 4 n-values
  const int rm = tid >> 5, rj = tid & 31;        // rebuild: row 0..15, chunk 0..31
  const int q1 = (q + 1) & 3, q2 = (q + 2) & 3, q3 = (q + 3) & 3;
  const int i1 = (rm << 7) + (q1 << 5) + rj;
  const int i2 = (rm << 7) + (q2 << 5) + rj;
  const int i3 = (rm << 7) + (q3 << 5) + rj;

  // per-wave flags: flags[g][q][w] (monotonic step counter, single writer)
  unsigned int* fgrp = flags + (g << 5);               // 32 words per group
  unsigned int* myflag = fgrp + (q << 3) + w;
  // lanes 0..23 poll sibling wave flags: sibling (lane>>3), wave (lane&7)
  unsigned int* pollflag = fgrp + ((((q + 1 + (lane >> 3)) & 3) << 3) + (lane & 7));

  // prefetch xi for t = 0 (Xi lives in HO, written by xi_gemm)
  float4 xi = *(const float4*)(HO + (long)(r0 + lm) * DLAT + ncol);

  for (int t = 0; t < T_STEPS; ++t) {
    char* cur = sB + ((t & 1) << 14);
    char* nxt = sB + (((t + 1) & 1) << 14);

    // z^T[n][m] = sum_k Wh[n][k] * h[m][k]; 4 chains (depth 4) for MFMA-latency ILP
    f32x4 a0 = f32x4{0.f, 0.f, 0.f, 0.f};
    f32x4 a1 = f32x4{0.f, 0.f, 0.f, 0.f};
    f32x4 a2 = f32x4{0.f, 0.f, 0.f, 0.f};
    f32x4 a3 = f32x4{0.f, 0.f, 0.f, 0.f};
    #pragma unroll
    for (int kq = 0; kq < 16; kq += 4) {
      bf16x8 hb0 = __builtin_bit_cast(bf16x8, *(uint4*)(cur + ((hbase + kq * 64) ^ mask)));
      bf16x8 hb1 = __builtin_bit_cast(bf16x8, *(uint4*)(cur + ((hbase + (kq + 1) * 64) ^ mask)));
      bf16x8 hb2 = __builtin_bit_cast(bf16x8, *(uint4*)(cur + ((hbase + (kq + 2) * 64) ^ mask)));
      bf16x8 hb3 = __builtin_bit_cast(bf16x8, *(uint4*)(cur + ((hbase + (kq + 3) * 64) ^ mask)));
      a0 = __builtin_amdgcn_mfma_f32_16x16x32_bf16(
          __builtin_bit_cast(bf16x8, wreg[kq]), hb0, a0, 0, 0, 0);
      a1 = __builtin_amdgcn_mfma_f32_16x16x32_bf16(
          __builtin_bit_cast(bf16x8, wreg[kq + 1]), hb1, a1, 0, 0, 0);
      a2 = __builtin_amdgcn_mfma_f32_16x16x32_bf16(
          __builtin_bit_cast(bf16x8, wreg[kq + 2]), hb2, a2, 0, 0, 0);
      a3 = __builtin_amdgcn_mfma_f32_16x16x32_bf16(
          __builtin_bit_cast(bf16x8, wreg[kq + 3]), hb3, a3, 0, 0, 0);
    }

    // h = tanh(z + xi)
    float hv[4];
    #pragma unroll
    for (int e = 0; e < 4; ++e) {
      float z = (a0[e] + a1[e]) + (a2[e] + a3[e]) + ((float*)&xi)[e];
      float ex = __expf(2.0f * z);
      hv[e] = 1.0f - 2.0f / (ex + 1.0f);
    }

    unsigned int pr01 = f2bf2(hv[0], hv[1]);
    unsigned int pr23 = f2bf2(hv[2], hv[3]);
    u64 v = (u64)pr01 | ((u64)pr23 << 32);

    if (t + 1 < T_STEPS) {
      u64* hxg = hgrp + ((long)(t & 1) << 14);   // parity slab 16384 u64 (covers 8 groups)

      // publish (8-B L3 write); drain OWN wave only; lane0 stores per-wave flag
      __hip_atomic_store(&hxg[pubi], v, __ATOMIC_RELAXED, __HIP_MEMORY_SCOPE_AGENT);
      asm volatile("s_waitcnt vmcnt(0)" ::: "memory");
      if (lane == 0)
        __hip_atomic_store(myflag, (unsigned int)(t + 1),
                           __ATOMIC_RELAXED, __HIP_MEMORY_SCOPE_AGENT);

      // overlap window: own-slice -> NEXT buffer, HO store, next-xi prefetch
      {
        int ax = ((lm << 10) + (ncol << 1)) ^ mask;
        *(u64*)(nxt + ax) = v;
        float4 o; o.x = hv[0]; o.y = hv[1]; o.z = hv[2]; o.w = hv[3];
        *(float4*)(HO + ((long)t * BATCH + r0 + lm) * DLAT + ncol) = o;
        xi = *(const float4*)(HO + ((long)(t + 1) * BATCH + r0 + lm) * DLAT + ncol);
      }

      // FUSED speculative poll + rebuild: lanes 0-23 watch the 24 sibling-wave flags;
      // data sampled in the iteration where all flags >= t+1 is provably post-publish.
      u64 d1, d2, d3;
      {
        const unsigned int want = (unsigned int)(t + 1);
        for (;;) {
          d1 = __hip_atomic_load(&hxg[i1], __ATOMIC_RELAXED, __HIP_MEMORY_SCOPE_AGENT);
          d2 = __hip_atomic_load(&hxg[i2], __ATOMIC_RELAXED, __HIP_MEMORY_SCOPE_AGENT);
          d3 = __hip_atomic_load(&hxg[i3], __ATOMIC_RELAXED, __HIP_MEMORY_SCOPE_AGENT);
          unsigned int fv = (lane < 24)
              ? __hip_atomic_load(pollflag, __ATOMIC_RELAXED, __HIP_MEMORY_SCOPE_AGENT)
              : want;
          if (!__any(fv < want)) break;
        }
      }
      asm volatile("" ::: "memory");

      // commit the 3 sibling quarters -> NEXT buffer
      {
        int ax1 = ((rm << 10) + (((q1 << 5) + rj) << 3)) ^ ((rm & 7) << 4);
        int ax2 = ((rm << 10) + (((q2 << 5) + rj) << 3)) ^ ((rm & 7) << 4);
        int ax3 = ((rm << 10) + (((q3 << 5) + rj) << 3)) ^ ((rm & 7) << 4);
        *(u64*)(nxt + ax1) = d1;
        *(u64*)(nxt + ax2) = d2;
        *(u64*)(nxt + ax3) = d3;
      }

      __syncthreads();   // single barrier: nxt fully built before next step's MFMA
    } else {
      float4 o; o.x = hv[0]; o.y = hv[1]; o.z = hv[2]; o.w = hv[3];
      *(float4*)(HO + ((long)t * BATCH + r0 + lm) * DLAT + ncol) = o;
    }
  }
}

extern "C" void kernel_launch(void* const* d_in, const int* in_sizes, int n_in,
                              void* d_out, int out_size, void* d_ws, size_t ws_size,
                              hipStream_t stream) {
  const float* X  = (const float*)d_in[0];
  const float* h0 = (const float*)d_in[1];
  const float* Wi = (const float*)d_in[2];
  const float* bi = (const float*)d_in[3];
  const float* Wh = (const float*)d_in[4];
  const float* bh = (const float*)d_in[5];
  float* out = (float*)d_out;

  // ws: [0,512K) WhP bf16; [512K,768K) hx (2 parities x 8 groups x 16 KB);
  //     [768K,769K) flags u32[8][4][8] = 1 KB (per-wave monotonic counters)
  unsigned int* whp   = (unsigned int*)d_ws;
  u64*          hx    = (u64*)((char*)d_ws + 524288);
  unsigned int* flags = (unsigned int*)((char*)d_ws + 786432);

  hipMemsetAsync(flags, 0, 1024, stream);   // re-zeroed on every (graph) replay

  hipFuncSetAttribute((const void*)xi_gemm, hipFuncAttributeMaxDynamicSharedMemorySize, 131584);

  pk_wh<<<128, 256, 0, stream>>>(Wh, whp);
  xi_gemm<<<dim3(512, 4), 256, 131584, stream>>>(X, Wi, bi, bh, out);
  rnn_scan<<<32, 512, 0, stream>>>(h0, (const unsigned short*)whp, out, hx, flags);
}

// Round 22
// 1313.159 us; speedup vs baseline: 1.4191x; 1.4191x over previous
//
#include <hip/hip_runtime.h>

#define T_STEPS 512
#define BATCH   128
#define DIN     256
#define DLAT    512

typedef __bf16 bf16x8 __attribute__((ext_vector_type(8)));
typedef float  f32x4  __attribute__((ext_vector_type(4)));
typedef int    i32x4  __attribute__((ext_vector_type(4)));
typedef unsigned long long u64;

__device__ __forceinline__ unsigned int f2bf2(float a, float b) {
  unsigned int ua = __float_as_uint(a);
  unsigned int ub = __float_as_uint(b);
  ua = (ua + 0x7FFFu + ((ua >> 16) & 1u)) >> 16;
  ub = (ub + 0x7FFFu + ((ub >> 16) & 1u)) >> 16;
  return ua | (ub << 16);
}

__device__ __forceinline__ uint4 pack8(float4 f0, float4 f1) {
  uint4 r;
  r.x = f2bf2(f0.x, f0.y);
  r.y = f2bf2(f0.z, f0.w);
  r.z = f2bf2(f1.x, f1.y);
  r.w = f2bf2(f1.z, f1.w);
  return r;
}

// ---------------- Kernel P: prepack Wh fp32 -> bf16 row-major in workspace ----------------
extern "C" __global__ __launch_bounds__(256) void pk_wh(
    const float* __restrict__ Wh, unsigned int* __restrict__ out) {
  int idx = blockIdx.x * 256 + threadIdx.x;   // 0..32767, 8 f32 each
  const float* src = Wh + (long)idx * 8;
  float4 f0 = *(const float4*)src;
  float4 f1 = *(const float4*)(src + 4);
  uint4 v = pack8(f0, f1);
  *(uint4*)(out + (long)idx * 4) = v;
}

// ---------------- Kernel A: Xi = X @ Wi^T + (bi + bh), written into d_out ----------------
extern "C" __global__ __launch_bounds__(256) void xi_gemm(
    const float* __restrict__ X, const float* __restrict__ Wi,
    const float* __restrict__ bi, const float* __restrict__ bh,
    float* __restrict__ XiOut) {
  extern __shared__ char smem[];
  char*  sX    = smem;                      // 65536 B: [128 rows][512 B] swizzled
  char*  sW    = smem + 65536;              // 65536 B
  float* sBias = (float*)(smem + 131072);   // 128 floats

  const int tid = threadIdx.x;
  const long m0 = (long)blockIdx.x * 128;   // over T*B = 65536
  const int  n0 = blockIdx.y * 128;         // over DLAT

  #pragma unroll
  for (int c = 0; c < 16; ++c) {
    int id = c * 256 + tid;                 // 0..4095
    int r  = id >> 5;                       // 0..127
    int kc = (id & 31) << 3;                // 0..248
    const float* sx = X + (m0 + r) * DIN + kc;
    float4 a0 = *(const float4*)sx;
    float4 a1 = *(const float4*)(sx + 4);
    int ax = ((r << 9) + (kc << 1)) ^ ((r & 7) << 4);
    *(uint4*)(sX + ax) = pack8(a0, a1);
    const float* sw = Wi + (n0 + r) * DIN + kc;
    float4 b0 = *(const float4*)sw;
    float4 b1 = *(const float4*)(sw + 4);
    *(uint4*)(sW + ax) = pack8(b0, b1);
  }
  if (tid < 128) sBias[tid] = bi[n0 + tid] + bh[n0 + tid];
  __syncthreads();

  const int w = tid >> 6, lane = tid & 63;
  const int wm = (w >> 1) * 64, wn = (w & 1) * 64;
  const int lm = lane & 15, lq = lane >> 4;

  f32x4 acc[4][4];
  #pragma unroll
  for (int nt = 0; nt < 4; ++nt) {
    float bv = sBias[wn + nt * 16 + lm];
    #pragma unroll
    for (int mt = 0; mt < 4; ++mt) acc[mt][nt] = f32x4{bv, bv, bv, bv};
  }

  #pragma unroll
  for (int k0 = 0; k0 < 8; ++k0) {
    int kb = (k0 << 6) + (lq << 4);
    bf16x8 af[4], bfr[4];
    #pragma unroll
    for (int mt = 0; mt < 4; ++mt) {
      int row = wm + mt * 16 + lm;
      int ax = ((row << 9) + kb) ^ ((row & 7) << 4);
      af[mt] = __builtin_bit_cast(bf16x8, *(uint4*)(sX + ax));
    }
    #pragma unroll
    for (int nt = 0; nt < 4; ++nt) {
      int row = wn + nt * 16 + lm;
      int ax = ((row << 9) + kb) ^ ((row & 7) << 4);
      bfr[nt] = __builtin_bit_cast(bf16x8, *(uint4*)(sW + ax));
    }
    #pragma unroll
    for (int mt = 0; mt < 4; ++mt)
      #pragma unroll
      for (int nt = 0; nt < 4; ++nt)
        acc[mt][nt] = __builtin_amdgcn_mfma_f32_16x16x32_bf16(af[mt], bfr[nt], acc[mt][nt], 0, 0, 0);
  }

  #pragma unroll
  for (int mt = 0; mt < 4; ++mt) {
    #pragma unroll
    for (int e = 0; e < 4; ++e) {
      long m = m0 + wm + mt * 16 + (lq << 2) + e;
      float* dst = XiOut + m * DLAT + n0 + wn + lm;
      #pragma unroll
      for (int nt = 0; nt < 4; ++nt)
        dst[nt * 16] = acc[mt][nt][e];
    }
  }
}

// ---------------- Kernel B: n-split x4 recurrence, L3-coherent exchange ----------------
// 32 blocks = 8 batch-groups x 4 n-quarters; 512 threads; wave w owns ONE n-tile
// (nt = q*128 + w*16), Wh slice = wreg[16] = 64 regs (AGPR-resident via AV class).
// LDS = 2 x 16 KB sH double-buffer + 2-word counter.
// Skeleton = r19 (best, 1163 us): lean 8-B bf16 publish, single per-(q,t) block flag,
// fused speculative poll+rebuild (flag + same-iteration data sampling).
// r21 lesson: 8 per-wave flags add slowest-wave skew to the REMOTE wait -- keep ONE
// block-synced flag. This round's single change: barrier #1 -> LDS COUNTER. Each wave
// publishes, drains its OWN vmcnt(0), lane0 ds_atomic_adds cnt[t&1]; the wave seeing
// old==7 (all 8 publishes at L3) resets the counter and stores the block flag. Same
// signal as r19, fired ~a barrier earlier; other waves fall straight into the overlap
// window. Removing barrier #1 is safe because sH is double-buffered: step t MFMA-reads
// cur while own-slice+commit write nxt (r15 race class impossible). One barrier/step.
// Counter-slot reuse (t vs t+2) separated by two block barriers. Depth-2 parity audit:
// Y's step-t slab reads < Y's barrier(t) < Y's flag[t+1] (program order) < X's
// detect(t+1) < X's barrier(t+1) < X's publish(t+2) overwrite. flags[g][q][t] zeroed
// per launch (graph-safe).
extern "C" __global__ __launch_bounds__(512, 2) void rnn_scan(
    const float* __restrict__ h0, const unsigned short* __restrict__ WhP,
    float* __restrict__ HO, u64* __restrict__ hx,
    unsigned int* __restrict__ flags) {
  __shared__ uint4 sHbuf[2048];       // 32 KB: two 16 KB h buffers, XOR-swizzled rows
  __shared__ unsigned int cnt[2];     // per-parity publish counters
  char* sB = (char*)sHbuf;

  const int tid = threadIdx.x;
  const int w = tid >> 6, lane = tid & 63;
  const int lm = lane & 15, lq = lane >> 4;
  const int g  = blockIdx.x & 7;      // batch group: rows [g*16, g*16+16)
  const int q  = blockIdx.x >> 3;     // n-quarter:  cols [q*128, q*128+128)
  const int r0 = g << 4;
  const int nt = (q << 7) + (w << 4); // wave's n-tile

  // Wh slice: lane holds Wh[nt+lm][kq*32 + lq*8 .. +7], kq = 0..15 (64 regs)
  i32x4 wreg[16];
  {
    const unsigned short* base = WhP + (nt + lm) * DLAT + (lq << 3);
    #pragma unroll
    for (int kq = 0; kq < 16; ++kq)
      wreg[kq] = *(const i32x4*)(base + kq * 32);
    #pragma unroll
    for (int kq = 0; kq < 16; ++kq)
      asm("" : "+v"(wreg[kq]));   // anti-remat pin (asm def)
  }

  // initial h from h0 into buffer 0: 16 rows x 64 chunks(16B) = 1024 -> 2 iters
  #pragma unroll
  for (int c = 0; c < 2; ++c) {
    int id = c * 512 + tid;
    int m = id >> 6, kc = (id & 63) << 3;
    const float* src = h0 + (r0 + m) * DLAT + kc;
    float4 f0 = *(const float4*)src;
    float4 f1 = *(const float4*)(src + 4);
    int ax = ((m << 10) + (kc << 1)) ^ ((m & 7) << 4);
    *(uint4*)(sB + ax) = pack8(f0, f1);
  }
  if (tid == 0) { cnt[0] = 0u; cnt[1] = 0u; }
  __syncthreads();

  const int mask  = (lm & 7) << 4;
  const int hbase = (lm << 10) + (lq << 4);
  const int ncol  = nt + (lq << 2);              // thread's 4 consecutive n (row m = lm)
  unsigned int* fgrp = flags + (g << 11);        // flags[g][q][t]: (q<<9)+t
  const int sq = (q + 1 + lane) & 3;             // lanes 0..2 -> the 3 siblings
  const int rm = tid >> 5, rj = tid & 31;        // rebuild: row 0..15, chunk 0..31
  const int q1 = (q + 1) & 3, q2 = (q + 2) & 3, q3 = (q + 3) & 3;
  const int i1 = (rm << 7) + (q1 << 5) + rj;
  const int i2 = (rm << 7) + (q2 << 5) + rj;
  const int i3 = (rm << 7) + (q3 << 5) + rj;

  // prefetch xi for t = 0 (Xi lives in HO, written by xi_gemm)
  float4 xi = *(const float4*)(HO + (long)(r0 + lm) * DLAT + ncol);

  for (int t = 0; t < T_STEPS; ++t) {
    char* cur = sB + ((t & 1) << 14);
    char* nxt = sB + (((t + 1) & 1) << 14);

    // z^T[n][m] = sum_k Wh[n][k] * h[m][k]; 4 chains (depth 4) for MFMA-latency ILP
    f32x4 a0 = f32x4{0.f, 0.f, 0.f, 0.f};
    f32x4 a1 = f32x4{0.f, 0.f, 0.f, 0.f};
    f32x4 a2 = f32x4{0.f, 0.f, 0.f, 0.f};
    f32x4 a3 = f32x4{0.f, 0.f, 0.f, 0.f};
    #pragma unroll
    for (int kq = 0; kq < 16; kq += 4) {
      bf16x8 hb0 = __builtin_bit_cast(bf16x8, *(uint4*)(cur + ((hbase + kq * 64) ^ mask)));
      bf16x8 hb1 = __builtin_bit_cast(bf16x8, *(uint4*)(cur + ((hbase + (kq + 1) * 64) ^ mask)));
      bf16x8 hb2 = __builtin_bit_cast(bf16x8, *(uint4*)(cur + ((hbase + (kq + 2) * 64) ^ mask)));
      bf16x8 hb3 = __builtin_bit_cast(bf16x8, *(uint4*)(cur + ((hbase + (kq + 3) * 64) ^ mask)));
      a0 = __builtin_amdgcn_mfma_f32_16x16x32_bf16(
          __builtin_bit_cast(bf16x8, wreg[kq]), hb0, a0, 0, 0, 0);
      a1 = __builtin_amdgcn_mfma_f32_16x16x32_bf16(
          __builtin_bit_cast(bf16x8, wreg[kq + 1]), hb1, a1, 0, 0, 0);
      a2 = __builtin_amdgcn_mfma_f32_16x16x32_bf16(
          __builtin_bit_cast(bf16x8, wreg[kq + 2]), hb2, a2, 0, 0, 0);
      a3 = __builtin_amdgcn_mfma_f32_16x16x32_bf16(
          __builtin_bit_cast(bf16x8, wreg[kq + 3]), hb3, a3, 0, 0, 0);
    }

    // h = tanh(z + xi)
    float hv[4];
    #pragma unroll
    for (int e = 0; e < 4; ++e) {
      float z = (a0[e] + a1[e]) + (a2[e] + a3[e]) + ((float*)&xi)[e];
      float ex = __expf(2.0f * z);
      hv[e] = 1.0f - 2.0f / (ex + 1.0f);
    }

    unsigned int pr01 = f2bf2(hv[0], hv[1]);
    unsigned int pr23 = f2bf2(hv[2], hv[3]);
    u64 v = (u64)pr01 | ((u64)pr23 << 32);

    if (t + 1 < T_STEPS) {
      u64* hxg = hx + ((long)(t & 1) << 14) + ((long)g << 11);  // parity 16384, group 2048 u64

      // publish (8-B L3 write); drain OWN wave; count in via LDS; 8th wave fires flag
      __hip_atomic_store(&hxg[(lm << 7) + (ncol >> 2)], v,
                         __ATOMIC_RELAXED, __HIP_MEMORY_SCOPE_AGENT);
      asm volatile("s_waitcnt vmcnt(0)" ::: "memory");
      if (lane == 0) {
        unsigned int old = atomicAdd(&cnt[t & 1], 1u);
        if (old == 7u) {
          cnt[t & 1] = 0u;   // reset for t+2 (two barriers away for every wave)
          __hip_atomic_store(&fgrp[(q << 9) + t], 1u,
                             __ATOMIC_RELAXED, __HIP_MEMORY_SCOPE_AGENT);
        }
      }

      // overlap window: own-slice -> NEXT buffer, HO store, next-xi prefetch
      {
        int ax = ((lm << 10) + (ncol << 1)) ^ mask;
        *(u64*)(nxt + ax) = v;
        float4 o; o.x = hv[0]; o.y = hv[1]; o.z = hv[2]; o.w = hv[3];
        *(float4*)(HO + ((long)t * BATCH + r0 + lm) * DLAT + ncol) = o;
        xi = *(const float4*)(HO + ((long)(t + 1) * BATCH + r0 + lm) * DLAT + ncol);
      }

      // FUSED speculative poll + rebuild (r19): lanes 0-2 watch the 3 sibling flags;
      // data sampled in the iteration where all flags are set is provably post-publish.
      u64 d1, d2, d3;
      for (;;) {
        d1 = __hip_atomic_load(&hxg[i1], __ATOMIC_RELAXED, __HIP_MEMORY_SCOPE_AGENT);
        d2 = __hip_atomic_load(&hxg[i2], __ATOMIC_RELAXED, __HIP_MEMORY_SCOPE_AGENT);
        d3 = __hip_atomic_load(&hxg[i3], __ATOMIC_RELAXED, __HIP_MEMORY_SCOPE_AGENT);
        unsigned int fv = (lane < 3)
            ? __hip_atomic_load(&fgrp[(sq << 9) + t], __ATOMIC_RELAXED, __HIP_MEMORY_SCOPE_AGENT)
            : 1u;
        if (!__any(fv == 0u)) break;
      }
      asm volatile("" ::: "memory");

      // commit the 3 sibling quarters -> NEXT buffer
      {
        int ax1 = ((rm << 10) + (((q1 << 5) + rj) << 3)) ^ ((rm & 7) << 4);
        int ax2 = ((rm << 10) + (((q2 << 5) + rj) << 3)) ^ ((rm & 7) << 4);
        int ax3 = ((rm << 10) + (((q3 << 5) + rj) << 3)) ^ ((rm & 7) << 4);
        *(u64*)(nxt + ax1) = d1;
        *(u64*)(nxt + ax2) = d2;
        *(u64*)(nxt + ax3) = d3;
      }

      __syncthreads();   // single barrier: nxt fully built before next step's MFMA
    } else {
      float4 o; o.x = hv[0]; o.y = hv[1]; o.z = hv[2]; o.w = hv[3];
      *(float4*)(HO + ((long)t * BATCH + r0 + lm) * DLAT + ncol) = o;
    }
  }
}

extern "C" void kernel_launch(void* const* d_in, const int* in_sizes, int n_in,
                              void* d_out, int out_size, void* d_ws, size_t ws_size,
                              hipStream_t stream) {
  const float* X  = (const float*)d_in[0];
  const float* h0 = (const float*)d_in[1];
  const float* Wi = (const float*)d_in[2];
  const float* bi = (const float*)d_in[3];
  const float* Wh = (const float*)d_in[4];
  const float* bh = (const float*)d_in[5];
  float* out = (float*)d_out;

  // ws: [0,512K) WhP bf16; [512K,768K) hx (2 parities x 8 groups x 16 KB);
  //     [768K,832K) flags u32[8][4][512] = 64 KB (single-writer, zeroed per launch)
  unsigned int* whp   = (unsigned int*)d_ws;
  u64*          hx    = (u64*)((char*)d_ws + 524288);
  unsigned int* flags = (unsigned int*)((char*)d_ws + 786432);

  hipMemsetAsync(flags, 0, 65536, stream);   // re-zeroed on every (graph) replay

  hipFuncSetAttribute((const void*)xi_gemm, hipFuncAttributeMaxDynamicSharedMemorySize, 131584);

  pk_wh<<<128, 256, 0, stream>>>(Wh, whp);
  xi_gemm<<<dim3(512, 4), 256, 131584, stream>>>(X, Wi, bi, bh, out);
  rnn_scan<<<32, 512, 0, stream>>>(h0, (const unsigned short*)whp, out, hx, flags);
}